// Round 9
// baseline (385.076 us; speedup 1.0000x reference)
//
#include <hip/hip_runtime.h>
#include <stdint.h>

typedef unsigned short u16;
typedef unsigned int   u32;
typedef __attribute__((ext_vector_type(8))) short bh8;   // 8 bf16
typedef __attribute__((ext_vector_type(4))) float f32x4; // MFMA C/D

#define SCALE 0.17677669529663687f   // 1/sqrt(32)
#define MFMA  __builtin_amdgcn_mfma_f32_16x16x32_bf16

// ws layout (u16 units)
#define WS_QKV  0         // qkvT  [384][128] bf16 (q rows pre-scaled)
#define WS_PROJ 49152     // projT [128][128] bf16, k-permuted (matches interleaved ao)
#define WS_F1   65536     // f1T   [512][128] bf16, n2g-scaled rows
#define WS_F2   131072    // f2T   [128][512] bf16, natural k order
#define WS_M    196608    // f32[4cls][4h][16 rtct][64 lane][4 jr]
#define WS_QB   327680    // f32[384] qkv bias (q part pre-scaled)
#define WS_S1   328448    // f32[512]  S1[j] = sum_c n2g[c]*f1w[c][j]
#define WS_T1   329472    // f32[512]  T1[j] = f1b[j] + sum_c n2b[c]*f1w[c][j]

__device__ __forceinline__ u16 f2bf(float f){
    u32 i; __builtin_memcpy(&i,&f,4); i += 0x7fffu + ((i>>16)&1u); return (u16)(i>>16);
}
__device__ __forceinline__ u32 cvtpk(float lo, float hi){
    u32 r; asm("v_cvt_pk_bf16_f32 %0, %1, %2" : "=v"(r) : "v"(lo), "v"(hi)); return r;
}
__device__ __forceinline__ float rcpf(float v){
    float r; asm("v_rcp_f32 %0, %1" : "=v"(r) : "v"(v)); return r;
}
// exact-quality GELU: Abramowitz-Stegun 7.1.26 erf (|err|<=1.5e-7)
__device__ __forceinline__ float gelu_f(float x){
    float ax = fabsf(x);
    float z  = ax * 0.70710678118654752f;
    float t  = rcpf(fmaf(0.3275911f, z, 1.0f));
    float p  = t * fmaf(t, fmaf(t, fmaf(t, fmaf(t, 1.061405429f, -1.453152027f),
                                        1.421413741f), -0.284496736f), 0.254829592f);
    float e  = __expf(-z * z);
    float y  = fmaf(-p, e, 1.0f);          // erf(z)
    return fmaf(0.5f * ax, y, 0.5f * x);
}
union BH8U { bh8 v; u32 u[4]; };

// ---------------------------------------------------------------------------
// Prep: weights f32->bf16 (transposed/permuted/LN-folded), M table, S1/T1.
// (identical to round 8)
// ---------------------------------------------------------------------------
__global__ void prep_k(const float* __restrict__ qkvw, const float* __restrict__ projw,
                       const float* __restrict__ f1w,  const float* __restrict__ f2w,
                       const float* __restrict__ rel,  const float* __restrict__ qkvb,
                       const float* __restrict__ n2g,  const float* __restrict__ n2b,
                       const float* __restrict__ f1b,  u16* __restrict__ ws)
{
    int idx = blockIdx.x * 256 + threadIdx.x;
    if (idx < 49152) {
        int c = idx / 384, j = idx % 384;
        float v = qkvw[idx] * (j < 128 ? SCALE : 1.0f);
        ws[WS_QKV + j * 128 + c] = f2bf(v);
    } else if (idx < 65536) {
        int i = idx - 49152; int k = i >> 7, j = i & 127;
        int pk = (k & ~31) | ((k & 15) << 1) | ((k >> 4) & 1);
        ws[WS_PROJ + j * 128 + pk] = f2bf(projw[i]);
    } else if (idx < 131072) {
        int i = idx - 65536; int c = i >> 9, j = i & 511;
        ws[WS_F1 + j * 128 + c] = f2bf(f1w[i] * n2g[c]);
    } else if (idx < 196608) {
        int i = idx - 131072; int k = i >> 7, j = i & 127;
        ws[WS_F2 + j * 512 + k] = f2bf(f2w[i]);
    } else if (idx < 262144) {
        int m = idx - 196608;
        int jr = m & 3, lane = (m >> 2) & 63, tct = (m >> 8) & 15;
        int h = (m >> 12) & 3, cls = (m >> 14) & 3;
        int rt = tct >> 2, ct = tct & 3;
        int row = rt * 16 + (lane >> 4) * 4 + jr, key = ct * 16 + (lane & 15);
        float v;
        if (row < 49 && key < 49) {
            int ri = row / 7, rc = row % 7, ki = key / 7, kc = key % 7;
            v = rel[((ri - ki + 6) * 13 + (rc - kc + 6)) * 4 + h];
            int rH = (cls & 2) ? (ri < 4 ? 1 : 2) : 0, rW = (cls & 1) ? (rc < 4 ? 1 : 2) : 0;
            int kH = (cls & 2) ? (ki < 4 ? 1 : 2) : 0, kW = (cls & 1) ? (kc < 4 ? 1 : 2) : 0;
            if (rH * 3 + rW != kH * 3 + kW) v -= 100.0f;
        } else v = -30000.0f;
        ((float*)(ws + WS_M))[m] = v;
    } else if (idx < 262528) {
        int j = idx - 262144;
        ((float*)(ws + WS_QB))[j] = qkvb[j] * (j < 128 ? SCALE : 1.0f);
    } else if (idx < 263040) {
        int j = idx - 262528;
        float s1 = 0.f, t1 = 0.f;
        for (int c = 0; c < 128; ++c) {
            float w = f1w[c * 512 + j];
            s1 = fmaf(n2g[c], w, s1);
            t1 = fmaf(n2b[c], w, t1);
        }
        ((float*)(ws + WS_S1))[j] = s1;
        ((float*)(ws + WS_T1))[j] = f1b[j] + t1;
    }
}

// ---------------------------------------------------------------------------
// Attention: 1 block = one 7x7 window, 4 waves (wave = head). 50 KB LDS.
// (identical to round-6/8 version, known-good)
// ---------------------------------------------------------------------------
__global__ __launch_bounds__(256, 3) void swin_attn_k(
    const float* __restrict__ x, const float* __restrict__ n1g, const float* __restrict__ n1b,
    const float* __restrict__ projb, const u16* __restrict__ ws, float* __restrict__ out)
{
    __shared__ u16 arena[16384];   // xn[64][136] -> P[4h][64][64] (swz) -> ao[64][136]
    __shared__ u16 vt[9216];       // per head: vT[32][72]
    const int tid = threadIdx.x, h = tid >> 6, lane = tid & 63;
    const int c15 = lane & 15, g = lane >> 4;
    const int m = blockIdx.x, b = m >> 8, hb = (m >> 4) & 15, wb = m & 15;
    const int cls = ((hb == 15) ? 2 : 0) | ((wb == 15) ? 1 : 0);
    const float* QB = (const float*)(ws + WS_QB);
    const float* Mb = (const float*)(ws + WS_M) + (size_t)((cls * 4 + h) * 16) * 256;

    // ---- LN1 + shift -> xn bf16 (4-lane teams; 16 tokens per wave) ----
    {
        const int t = h * 16 + (lane >> 2), ss = lane & 3;
        if (t < 49) {
            const int td = (t * 37) >> 8, tm = t - td * 7;
            int hs = hb * 7 + td + 3;  if (hs >= 112) hs -= 112;
            int wsw = wb * 7 + tm + 3; if (wsw >= 112) wsw -= 112;
            const float* px = x + (size_t)((b * 112 + hs) * 112 + wsw) * 128 + ss * 32;
            float4 xv[8];
            #pragma unroll
            for (int i = 0; i < 8; ++i) xv[i] = *(const float4*)(px + i * 4);
            float s = 0.f, q = 0.f;
            #pragma unroll
            for (int i = 0; i < 8; ++i) {
                s += xv[i].x + xv[i].y + xv[i].z + xv[i].w;
                q += xv[i].x*xv[i].x + xv[i].y*xv[i].y + xv[i].z*xv[i].z + xv[i].w*xv[i].w;
            }
            s += __shfl_xor(s, 1); q += __shfl_xor(q, 1);
            s += __shfl_xor(s, 2); q += __shfl_xor(q, 2);
            float mean = s * (1.f/128.f), var = q * (1.f/128.f) - mean * mean;
            float rstd = rsqrtf(var + 1e-5f);
            const float* pg = n1g + ss * 32; const float* pb = n1b + ss * 32;
            #pragma unroll
            for (int i = 0; i < 4; ++i) {
                float4 a = xv[2*i], c = xv[2*i+1];
                float4 g1 = *(const float4*)(pg + i*8),  g2 = *(const float4*)(pg + i*8 + 4);
                float4 b1 = *(const float4*)(pb + i*8),  b2 = *(const float4*)(pb + i*8 + 4);
                uint4 w;
                w.x = cvtpk((a.x-mean)*rstd*g1.x + b1.x, (a.y-mean)*rstd*g1.y + b1.y);
                w.y = cvtpk((a.z-mean)*rstd*g1.z + b1.z, (a.w-mean)*rstd*g1.w + b1.w);
                w.z = cvtpk((c.x-mean)*rstd*g2.x + b2.x, (c.y-mean)*rstd*g2.y + b2.y);
                w.w = cvtpk((c.z-mean)*rstd*g2.z + b2.z, (c.w-mean)*rstd*g2.w + b2.w);
                *(uint4*)&arena[t * 136 + ss * 32 + i * 8] = w;
            }
        } else {
            #pragma unroll
            for (int i = 0; i < 4; ++i) *(uint4*)&arena[t * 136 + (lane & 3) * 32 + i * 8] = (uint4){0,0,0,0};
        }
    }
    __syncthreads();

    // ---- v = xn @ Wv  -> vT in LDS ----
    {
        bh8 avf[2][4];
        #pragma unroll
        for (int jt = 0; jt < 2; ++jt)
            #pragma unroll
            for (int kc = 0; kc < 4; ++kc)
                avf[jt][kc] = *(const bh8*)&ws[WS_QKV + (256 + h*32 + jt*16 + c15)*128 + kc*32 + g*8];
        const float vb0 = QB[256 + h*32 + c15], vb1 = QB[256 + h*32 + 16 + c15];
        #pragma unroll
        for (int tt = 0; tt < 4; ++tt) {
            bh8 xf[4];
            #pragma unroll
            for (int kc = 0; kc < 4; ++kc)
                xf[kc] = *(const bh8*)&arena[(tt*16 + c15)*136 + kc*32 + g*8];
            f32x4 D0 = {0,0,0,0}, D1 = {0,0,0,0};
            #pragma unroll
            for (int kc = 0; kc < 4; ++kc) { D0 = MFMA(xf[kc], avf[0][kc], D0, 0,0,0); D1 = MFMA(xf[kc], avf[1][kc], D1, 0,0,0); }
            uint2 p0, p1;
            p0.x = cvtpk(D0[0]+vb0, D0[1]+vb0); p0.y = cvtpk(D0[2]+vb0, D0[3]+vb0);
            p1.x = cvtpk(D1[0]+vb1, D1[1]+vb1); p1.y = cvtpk(D1[2]+vb1, D1[3]+vb1);
            *(uint2*)&vt[h*2304 + c15*72        + tt*16 + g*4] = p0;
            *(uint2*)&vt[h*2304 + (16+c15)*72   + tt*16 + g*4] = p1;
        }
    }

    // ---- q,k swapped-operand MFMA: fragments straight into registers ----
    bh8 qf[4], kf[4];
    {
        bh8 aqf[2][4], akf[2][4];
        #pragma unroll
        for (int jt = 0; jt < 2; ++jt)
            #pragma unroll
            for (int kc = 0; kc < 4; ++kc) {
                aqf[jt][kc] = *(const bh8*)&ws[WS_QKV + (      h*32 + jt*16 + c15)*128 + kc*32 + g*8];
                akf[jt][kc] = *(const bh8*)&ws[WS_QKV + (128 + h*32 + jt*16 + c15)*128 + kc*32 + g*8];
            }
        const float4 qb0 = *(const float4*)(QB + h*32 + g*4);
        const float4 qb1 = *(const float4*)(QB + h*32 + 16 + g*4);
        const float4 kb0 = *(const float4*)(QB + 128 + h*32 + g*4);
        const float4 kb1 = *(const float4*)(QB + 128 + h*32 + 16 + g*4);
        #pragma unroll
        for (int tt = 0; tt < 4; ++tt) {
            bh8 xf[4];
            #pragma unroll
            for (int kc = 0; kc < 4; ++kc)
                xf[kc] = *(const bh8*)&arena[(tt*16 + c15)*136 + kc*32 + g*8];
            f32x4 Dq0={0,0,0,0}, Dq1={0,0,0,0}, Dk0={0,0,0,0}, Dk1={0,0,0,0};
            #pragma unroll
            for (int kc = 0; kc < 4; ++kc) {
                Dq0 = MFMA(aqf[0][kc], xf[kc], Dq0, 0,0,0);
                Dq1 = MFMA(aqf[1][kc], xf[kc], Dq1, 0,0,0);
                Dk0 = MFMA(akf[0][kc], xf[kc], Dk0, 0,0,0);
                Dk1 = MFMA(akf[1][kc], xf[kc], Dk1, 0,0,0);
            }
            BH8U qu, ku;
            qu.u[0] = cvtpk(Dq0[0]+qb0.x, Dq0[1]+qb0.y); qu.u[1] = cvtpk(Dq0[2]+qb0.z, Dq0[3]+qb0.w);
            qu.u[2] = cvtpk(Dq1[0]+qb1.x, Dq1[1]+qb1.y); qu.u[3] = cvtpk(Dq1[2]+qb1.z, Dq1[3]+qb1.w);
            ku.u[0] = cvtpk(Dk0[0]+kb0.x, Dk0[1]+kb0.y); ku.u[1] = cvtpk(Dk0[2]+kb0.z, Dk0[3]+kb0.w);
            ku.u[2] = cvtpk(Dk1[0]+kb1.x, Dk1[1]+kb1.y); ku.u[3] = cvtpk(Dk1[2]+kb1.z, Dk1[3]+kb1.w);
            qf[tt] = qu.v; kf[tt] = ku.v;
        }
    }
    __syncthreads();   // xn dead; P aliases arena

    // ---- QK^T with baked bias/mask as acc-init; softmax (no max pass) ----
    f32x4 p[4][4]; f32x4 inv4[4];
    #pragma unroll
    for (int rt = 0; rt < 4; ++rt) {
        #pragma unroll
        for (int ct = 0; ct < 4; ++ct) {
            f32x4 macc = *(const f32x4*)(Mb + (rt*4 + ct)*256 + lane*4);
            p[rt][ct] = MFMA(qf[rt], kf[ct], macc, 0,0,0);
        }
        #pragma unroll
        for (int ct = 0; ct < 4; ++ct)
            #pragma unroll
            for (int jr = 0; jr < 4; ++jr) p[rt][ct][jr] = __expf(p[rt][ct][jr]);
        f32x4 t = p[rt][0] + p[rt][1] + p[rt][2] + p[rt][3];
        #pragma unroll
        for (int jr = 0; jr < 4; ++jr) {
            float v = t[jr];
            v += __shfl_xor(v, 1); v += __shfl_xor(v, 2);
            v += __shfl_xor(v, 4); v += __shfl_xor(v, 8);
            inv4[rt][jr] = rcpf(v + 1e-30f);
        }
    }

    // ---- P (raw exp) -> swizzled LDS tile ----
    char* Pbase = (char*)arena + h * 8192;
    #pragma unroll
    for (int rt = 0; rt < 4; ++rt)
        #pragma unroll
        for (int jr = 0; jr < 4; ++jr) {
            const int row = rt*16 + g*4 + jr, sw = (row & 7) << 4;
            #pragma unroll
            for (int ct = 0; ct < 4; ++ct)
                *(u16*)(Pbase + ((row*128 + (ct*16 + c15)*2) ^ sw)) = f2bf(p[rt][ct][jr]);
        }
    asm volatile("s_waitcnt lgkmcnt(0)" ::: "memory");

    // ---- PV ----
    f32x4 o[4][2];
    #pragma unroll
    for (int rt = 0; rt < 4; ++rt) { o[rt][0] = (f32x4){0,0,0,0}; o[rt][1] = (f32x4){0,0,0,0}; }
    {
        bh8 vf[2][2];
        #pragma unroll
        for (int ct = 0; ct < 2; ++ct)
            #pragma unroll
            for (int kc = 0; kc < 2; ++kc)
                vf[ct][kc] = *(const bh8*)&vt[h*2304 + (ct*16 + c15)*72 + kc*32 + g*8];
        #pragma unroll
        for (int rt = 0; rt < 4; ++rt) {
            const int row = rt*16 + c15, sw = (row & 7) << 4;
            #pragma unroll
            for (int kc = 0; kc < 2; ++kc) {
                bh8 pa = *(const bh8*)(Pbase + ((row*128 + kc*64 + g*16) ^ sw));
                o[rt][0] = MFMA(pa, vf[0][kc], o[rt][0], 0,0,0);
                o[rt][1] = MFMA(pa, vf[1][kc], o[rt][1], 0,0,0);
            }
        }
    }
    __syncthreads();   // P reads + vt reads done; arena free for ao

    // ---- normalized attn-out -> ao ----
    #pragma unroll
    for (int rt = 0; rt < 4; ++rt)
        #pragma unroll
        for (int jr = 0; jr < 4; ++jr) {
            const int row = rt*16 + g*4 + jr;
            u32 pk_ = cvtpk(o[rt][0][jr] * inv4[rt][jr], o[rt][1][jr] * inv4[rt][jr]);
            *(u32*)&arena[row*136 + h*32 + 2*c15] = pk_;
        }
    __syncthreads();

    // ---- proj + residual + unshift scatter ----
    {
        bh8 wfp[2][4];
        #pragma unroll
        for (int ct2 = 0; ct2 < 2; ++ct2)
            #pragma unroll
            for (int kc = 0; kc < 4; ++kc)
                wfp[ct2][kc] = *(const bh8*)&ws[WS_PROJ + (h*32 + ct2*16 + c15)*128 + kc*32 + g*8];
        f32x4 pacc[4][2];
        #pragma unroll
        for (int rt = 0; rt < 4; ++rt) { pacc[rt][0] = (f32x4){0,0,0,0}; pacc[rt][1] = (f32x4){0,0,0,0}; }
        #pragma unroll
        for (int rt = 0; rt < 4; ++rt) {
            bh8 af[4];
            #pragma unroll
            for (int kc = 0; kc < 4; ++kc)
                af[kc] = *(const bh8*)&arena[(rt*16 + c15)*136 + kc*32 + g*8];
            #pragma unroll
            for (int kc = 0; kc < 4; ++kc) {
                pacc[rt][0] = MFMA(af[kc], wfp[0][kc], pacc[rt][0], 0,0,0);
                pacc[rt][1] = MFMA(af[kc], wfp[1][kc], pacc[rt][1], 0,0,0);
            }
        }
        const int col0 = h*32 + c15, col1 = col0 + 16;
        const float pb0 = projb[col0], pb1 = projb[col1];
        #pragma unroll
        for (int rt = 0; rt < 4; ++rt)
            #pragma unroll
            for (int jr = 0; jr < 4; ++jr) {
                const int t = rt*16 + g*4 + jr;
                if (t < 49) {
                    const int td = (t * 37) >> 8, tm = t - td * 7;
                    int hs = hb*7 + td + 3;  if (hs >= 112) hs -= 112;
                    int wsw = wb*7 + tm + 3; if (wsw >= 112) wsw -= 112;
                    const size_t base = (size_t)((b*112 + hs)*112 + wsw) * 128;
                    out[base + col0] = pacc[rt][0][jr] + pb0 + x[base + col0];
                    out[base + col1] = pacc[rt][1][jr] + pb1 + x[base + col1];
                }
            }
    }
}

// ---------------------------------------------------------------------------
// MLP: barrier-free, wave-autonomous. 256 thr = 4 waves; each wave owns 32
// tokens end-to-end (fc1 swapped-operand MFMA -> fold+GELU in-register ->
// wave-private XOR-swizzled LDS transpose -> fc2 MFMA -> residual).
// Weights stream from L2 per wave. ZERO __syncthreads. In-place on d_out.
// ---------------------------------------------------------------------------
__global__ __launch_bounds__(256, 2) void swin_mlp_k(
    float* __restrict__ xio, const float* __restrict__ f2b, const u16* __restrict__ ws)
{
    __shared__ char scratch[32768];   // [wave 4][rt 2][tok 16][h 128] bf16, swizzled
    const int tid = threadIdx.x, w = tid >> 6, lane = tid & 63;
    const int c15 = lane & 15, g = lane >> 4;
    const size_t T0 = (size_t)blockIdx.x * 128 + w * 32;
    const float* S1 = (const float*)(ws + WS_S1);
    const float* T1 = (const float*)(ws + WS_T1);
    char* SB0 = scratch + w * 8192;
    const int sw = (c15 & 7) << 4;

    // ---- x1 -> B-frags (raw bf16) + LN2 stats (2 shuffles) ----
    bh8 xB[2][4];
    float2 st[2];
    #pragma unroll
    for (int rt = 0; rt < 2; ++rt) {
        const float* px = xio + (T0 + rt*16 + c15) * 128 + g * 8;
        float s = 0.f, q = 0.f;
        #pragma unroll
        for (int kc = 0; kc < 4; ++kc) {
            float4 a = *(const float4*)(px + kc*32);
            float4 b = *(const float4*)(px + kc*32 + 4);
            s += a.x+a.y+a.z+a.w + b.x+b.y+b.z+b.w;
            q += a.x*a.x+a.y*a.y+a.z*a.z+a.w*a.w + b.x*b.x+b.y*b.y+b.z*b.z+b.w*b.w;
            BH8U u;
            u.u[0] = cvtpk(a.x, a.y); u.u[1] = cvtpk(a.z, a.w);
            u.u[2] = cvtpk(b.x, b.y); u.u[3] = cvtpk(b.z, b.w);
            xB[rt][kc] = u.v;
        }
        s += __shfl_xor(s, 16); q += __shfl_xor(q, 16);
        s += __shfl_xor(s, 32); q += __shfl_xor(q, 32);
        float mean = s * (1.f/128.f), var = q * (1.f/128.f) - mean * mean;
        float rstd = rsqrtf(var + 1e-5f);
        st[rt] = (float2){rstd, rstd * mean};
    }

    f32x4 acc[2][8];
    #pragma unroll
    for (int rt = 0; rt < 2; ++rt)
        #pragma unroll
        for (int ct = 0; ct < 8; ++ct) acc[rt][ct] = (f32x4){0,0,0,0};

    for (int chunk = 0; chunk < 4; ++chunk) {
        // ---- fc1 (swapped: D = W1T-frag x xB -> [j][tok]) + fold + GELU ----
        #pragma unroll
        for (int jt = 0; jt < 8; ++jt) {
            bh8 w1f[4];
            #pragma unroll
            for (int kc = 0; kc < 4; ++kc)
                w1f[kc] = *(const bh8*)&ws[WS_F1 + (chunk*128 + jt*16 + c15)*128 + kc*32 + g*8];
            float4 s1v = *(const float4*)(S1 + chunk*128 + jt*16 + g*4);
            float4 t1v = *(const float4*)(T1 + chunk*128 + jt*16 + g*4);
            #pragma unroll
            for (int rt = 0; rt < 2; ++rt) {
                f32x4 D = {0,0,0,0};
                #pragma unroll
                for (int kc = 0; kc < 4; ++kc) D = MFMA(w1f[kc], xB[rt][kc], D, 0,0,0);
                float h0 = gelu_f(fmaf(st[rt].x, D[0], fmaf(-st[rt].y, s1v.x, t1v.x)));
                float h1 = gelu_f(fmaf(st[rt].x, D[1], fmaf(-st[rt].y, s1v.y, t1v.y)));
                float h2 = gelu_f(fmaf(st[rt].x, D[2], fmaf(-st[rt].y, s1v.z, t1v.z)));
                float h3 = gelu_f(fmaf(st[rt].x, D[3], fmaf(-st[rt].y, s1v.w, t1v.w)));
                uint2 hp; hp.x = cvtpk(h0, h1); hp.y = cvtpk(h2, h3);
                // transpose via wave-private scratch: [tok=c15][j=jt*16+g*4..+3]
                *(uint2*)(SB0 + rt*4096 + ((c15*256 + jt*32 + g*8) ^ sw)) = hp;
            }
        }
        // ---- fc2 partial (A = h[tok][k] from scratch; per-wave DS in-order) ----
        #pragma unroll
        for (int kt = 0; kt < 4; ++kt) {
            bh8 hA0 = *(const bh8*)(SB0        + ((c15*256 + kt*64 + g*16) ^ sw));
            bh8 hA1 = *(const bh8*)(SB0 + 4096 + ((c15*256 + kt*64 + g*16) ^ sw));
            #pragma unroll
            for (int ct = 0; ct < 8; ++ct) {
                bh8 w2f = *(const bh8*)&ws[WS_F2 + (ct*16 + c15)*512 + chunk*128 + kt*32 + g*8];
                acc[0][ct] = MFMA(hA0, w2f, acc[0][ct], 0, 0, 0);
                acc[1][ct] = MFMA(hA1, w2f, acc[1][ct], 0, 0, 0);
            }
        }
    }

    // ---- residual (in place): out[tok][col] += acc + f2b ----
    float f2bv[8];
    #pragma unroll
    for (int ct = 0; ct < 8; ++ct) f2bv[ct] = f2b[ct*16 + c15];
    #pragma unroll
    for (int rt = 0; rt < 2; ++rt)
        #pragma unroll
        for (int jr = 0; jr < 4; ++jr) {
            float* pr = xio + (T0 + rt*16 + g*4 + jr) * 128 + c15;
            #pragma unroll
            for (int ct = 0; ct < 8; ++ct)
                pr[ct*16] += acc[rt][ct][jr] + f2bv[ct];
        }
}

extern "C" void kernel_launch(void* const* d_in, const int* in_sizes, int n_in,
                              void* d_out, int out_size, void* d_ws, size_t ws_size,
                              hipStream_t stream)
{
    const float* x    = (const float*)d_in[0];
    const float* n1g  = (const float*)d_in[1];
    const float* n1b  = (const float*)d_in[2];
    const float* qkvw = (const float*)d_in[3];
    const float* qkvb = (const float*)d_in[4];
    const float* rel  = (const float*)d_in[5];
    const float* pw   = (const float*)d_in[6];
    const float* pb   = (const float*)d_in[7];
    const float* n2g  = (const float*)d_in[8];
    const float* n2b  = (const float*)d_in[9];
    const float* f1w  = (const float*)d_in[10];
    const float* f1b  = (const float*)d_in[11];
    const float* f2w  = (const float*)d_in[12];
    const float* f2b  = (const float*)d_in[13];
    float* out = (float*)d_out;
    u16* ws = (u16*)d_ws;

    prep_k<<<1028, 256, 0, stream>>>(qkvw, pw, f1w, f2w, rel, qkvb, n2g, n2b, f1b, ws);
    swin_attn_k<<<4096, 256, 0, stream>>>(x, n1g, n1b, pb, ws, out);
    swin_mlp_k<<<1568, 256, 0, stream>>>(out, f2b, ws);
}

// Round 10
// 252.108 us; speedup vs baseline: 1.5274x; 1.5274x over previous
//
#include <hip/hip_runtime.h>
#include <stdint.h>

typedef unsigned short u16;
typedef unsigned int   u32;
typedef __attribute__((ext_vector_type(8))) short bh8;   // 8 bf16
typedef __attribute__((ext_vector_type(4))) float f32x4; // MFMA C/D

#define SCALE 0.17677669529663687f   // 1/sqrt(32)
#define MFMA  __builtin_amdgcn_mfma_f32_16x16x32_bf16

// ws layout (u16 units)
#define WS_QKV  0         // qkvT  [384][128] bf16 (q rows pre-scaled)
#define WS_PROJ 49152     // projT [128][128] bf16, k-permuted (matches interleaved ao)
#define WS_F1   65536     // f1T   [512][128] bf16, n2g-scaled rows
#define WS_F2   131072    // f2T   [128][512] bf16, k-PERMUTED (matches packed hbuf)
#define WS_M    196608    // f32[4cls][4h][16 rtct][64 lane][4 jr]
#define WS_QB   327680    // f32[384] qkv bias (q part pre-scaled)
#define WS_S1   328448    // f32[512]  S1[j] = sum_c n2g[c]*f1w[c][j]
#define WS_T1   329472    // f32[512]  T1[j] = f1b[j] + sum_c n2b[c]*f1w[c][j]

__device__ __forceinline__ u16 f2bf(float f){
    u32 i; __builtin_memcpy(&i,&f,4); i += 0x7fffu + ((i>>16)&1u); return (u16)(i>>16);
}
__device__ __forceinline__ u32 cvtpk(float lo, float hi){
    u32 r; asm("v_cvt_pk_bf16_f32 %0, %1, %2" : "=v"(r) : "v"(lo), "v"(hi)); return r;
}
__device__ __forceinline__ float rcpf(float v){
    float r; asm("v_rcp_f32 %0, %1" : "=v"(r) : "v"(v)); return r;
}
// exact-quality GELU: Abramowitz-Stegun 7.1.26 erf (|err|<=1.5e-7)
__device__ __forceinline__ float gelu_f(float x){
    float ax = fabsf(x);
    float z  = ax * 0.70710678118654752f;
    float t  = rcpf(fmaf(0.3275911f, z, 1.0f));
    float p  = t * fmaf(t, fmaf(t, fmaf(t, fmaf(t, 1.061405429f, -1.453152027f),
                                        1.421413741f), -0.284496736f), 0.254829592f);
    float e  = __expf(-z * z);
    float y  = fmaf(-p, e, 1.0f);          // erf(z)
    return fmaf(0.5f * ax, y, 0.5f * x);
}
union BH8U { bh8 v; u32 u[4]; };

// ---------------------------------------------------------------------------
// Prep: weights f32->bf16 (transposed/permuted/LN-folded), M table, S1/T1.
// ---------------------------------------------------------------------------
__global__ void prep_k(const float* __restrict__ qkvw, const float* __restrict__ projw,
                       const float* __restrict__ f1w,  const float* __restrict__ f2w,
                       const float* __restrict__ rel,  const float* __restrict__ qkvb,
                       const float* __restrict__ n2g,  const float* __restrict__ n2b,
                       const float* __restrict__ f1b,  u16* __restrict__ ws)
{
    int idx = blockIdx.x * 256 + threadIdx.x;
    if (idx < 49152) {
        int c = idx / 384, j = idx % 384;
        float v = qkvw[idx] * (j < 128 ? SCALE : 1.0f);
        ws[WS_QKV + j * 128 + c] = f2bf(v);
    } else if (idx < 65536) {
        int i = idx - 49152; int k = i >> 7, j = i & 127;
        int pk = (k & ~31) | ((k & 15) << 1) | ((k >> 4) & 1);
        ws[WS_PROJ + j * 128 + pk] = f2bf(projw[i]);
    } else if (idx < 131072) {
        int i = idx - 65536; int c = i >> 9, j = i & 511;
        ws[WS_F1 + j * 128 + c] = f2bf(f1w[i] * n2g[c]);
    } else if (idx < 196608) {               // f2w [512][128] -> [j][pi(k)] (R6 pairing)
        int i = idx - 131072; int k = i >> 7, j = i & 127;
        int pk = (k & ~31) | ((k & 15) << 1) | ((k >> 4) & 1);
        ws[WS_F2 + j * 512 + pk] = f2bf(f2w[i]);
    } else if (idx < 262144) {
        int m = idx - 196608;
        int jr = m & 3, lane = (m >> 2) & 63, tct = (m >> 8) & 15;
        int h = (m >> 12) & 3, cls = (m >> 14) & 3;
        int rt = tct >> 2, ct = tct & 3;
        int row = rt * 16 + (lane >> 4) * 4 + jr, key = ct * 16 + (lane & 15);
        float v;
        if (row < 49 && key < 49) {
            int ri = row / 7, rc = row % 7, ki = key / 7, kc = key % 7;
            v = rel[((ri - ki + 6) * 13 + (rc - kc + 6)) * 4 + h];
            int rH = (cls & 2) ? (ri < 4 ? 1 : 2) : 0, rW = (cls & 1) ? (rc < 4 ? 1 : 2) : 0;
            int kH = (cls & 2) ? (ki < 4 ? 1 : 2) : 0, kW = (cls & 1) ? (kc < 4 ? 1 : 2) : 0;
            if (rH * 3 + rW != kH * 3 + kW) v -= 100.0f;
        } else v = -30000.0f;
        ((float*)(ws + WS_M))[m] = v;
    } else if (idx < 262528) {
        int j = idx - 262144;
        ((float*)(ws + WS_QB))[j] = qkvb[j] * (j < 128 ? SCALE : 1.0f);
    } else if (idx < 263040) {
        int j = idx - 262528;
        float s1 = 0.f, t1 = 0.f;
        for (int c = 0; c < 128; ++c) {
            float w = f1w[c * 512 + j];
            s1 = fmaf(n2g[c], w, s1);
            t1 = fmaf(n2b[c], w, t1);
        }
        ((float*)(ws + WS_S1))[j] = s1;
        ((float*)(ws + WS_T1))[j] = f1b[j] + t1;
    }
}

// ---------------------------------------------------------------------------
// Attention: 1 block = one 7x7 window, 4 waves (wave = head). 50 KB LDS.
// (identical to round-6/8 version, known-good)
// ---------------------------------------------------------------------------
__global__ __launch_bounds__(256, 3) void swin_attn_k(
    const float* __restrict__ x, const float* __restrict__ n1g, const float* __restrict__ n1b,
    const float* __restrict__ projb, const u16* __restrict__ ws, float* __restrict__ out)
{
    __shared__ u16 arena[16384];   // xn[64][136] -> P[4h][64][64] (swz) -> ao[64][136]
    __shared__ u16 vt[9216];       // per head: vT[32][72]
    const int tid = threadIdx.x, h = tid >> 6, lane = tid & 63;
    const int c15 = lane & 15, g = lane >> 4;
    const int m = blockIdx.x, b = m >> 8, hb = (m >> 4) & 15, wb = m & 15;
    const int cls = ((hb == 15) ? 2 : 0) | ((wb == 15) ? 1 : 0);
    const float* QB = (const float*)(ws + WS_QB);
    const float* Mb = (const float*)(ws + WS_M) + (size_t)((cls * 4 + h) * 16) * 256;

    // ---- LN1 + shift -> xn bf16 (4-lane teams; 16 tokens per wave) ----
    {
        const int t = h * 16 + (lane >> 2), ss = lane & 3;
        if (t < 49) {
            const int td = (t * 37) >> 8, tm = t - td * 7;
            int hs = hb * 7 + td + 3;  if (hs >= 112) hs -= 112;
            int wsw = wb * 7 + tm + 3; if (wsw >= 112) wsw -= 112;
            const float* px = x + (size_t)((b * 112 + hs) * 112 + wsw) * 128 + ss * 32;
            float4 xv[8];
            #pragma unroll
            for (int i = 0; i < 8; ++i) xv[i] = *(const float4*)(px + i * 4);
            float s = 0.f, q = 0.f;
            #pragma unroll
            for (int i = 0; i < 8; ++i) {
                s += xv[i].x + xv[i].y + xv[i].z + xv[i].w;
                q += xv[i].x*xv[i].x + xv[i].y*xv[i].y + xv[i].z*xv[i].z + xv[i].w*xv[i].w;
            }
            s += __shfl_xor(s, 1); q += __shfl_xor(q, 1);
            s += __shfl_xor(s, 2); q += __shfl_xor(q, 2);
            float mean = s * (1.f/128.f), var = q * (1.f/128.f) - mean * mean;
            float rstd = rsqrtf(var + 1e-5f);
            const float* pg = n1g + ss * 32; const float* pb = n1b + ss * 32;
            #pragma unroll
            for (int i = 0; i < 4; ++i) {
                float4 a = xv[2*i], c = xv[2*i+1];
                float4 g1 = *(const float4*)(pg + i*8),  g2 = *(const float4*)(pg + i*8 + 4);
                float4 b1 = *(const float4*)(pb + i*8),  b2 = *(const float4*)(pb + i*8 + 4);
                uint4 w;
                w.x = cvtpk((a.x-mean)*rstd*g1.x + b1.x, (a.y-mean)*rstd*g1.y + b1.y);
                w.y = cvtpk((a.z-mean)*rstd*g1.z + b1.z, (a.w-mean)*rstd*g1.w + b1.w);
                w.z = cvtpk((c.x-mean)*rstd*g2.x + b2.x, (c.y-mean)*rstd*g2.y + b2.y);
                w.w = cvtpk((c.z-mean)*rstd*g2.z + b2.z, (c.w-mean)*rstd*g2.w + b2.w);
                *(uint4*)&arena[t * 136 + ss * 32 + i * 8] = w;
            }
        } else {
            #pragma unroll
            for (int i = 0; i < 4; ++i) *(uint4*)&arena[t * 136 + (lane & 3) * 32 + i * 8] = (uint4){0,0,0,0};
        }
    }
    __syncthreads();

    // ---- v = xn @ Wv  -> vT in LDS ----
    {
        bh8 avf[2][4];
        #pragma unroll
        for (int jt = 0; jt < 2; ++jt)
            #pragma unroll
            for (int kc = 0; kc < 4; ++kc)
                avf[jt][kc] = *(const bh8*)&ws[WS_QKV + (256 + h*32 + jt*16 + c15)*128 + kc*32 + g*8];
        const float vb0 = QB[256 + h*32 + c15], vb1 = QB[256 + h*32 + 16 + c15];
        #pragma unroll
        for (int tt = 0; tt < 4; ++tt) {
            bh8 xf[4];
            #pragma unroll
            for (int kc = 0; kc < 4; ++kc)
                xf[kc] = *(const bh8*)&arena[(tt*16 + c15)*136 + kc*32 + g*8];
            f32x4 D0 = {0,0,0,0}, D1 = {0,0,0,0};
            #pragma unroll
            for (int kc = 0; kc < 4; ++kc) { D0 = MFMA(xf[kc], avf[0][kc], D0, 0,0,0); D1 = MFMA(xf[kc], avf[1][kc], D1, 0,0,0); }
            uint2 p0, p1;
            p0.x = cvtpk(D0[0]+vb0, D0[1]+vb0); p0.y = cvtpk(D0[2]+vb0, D0[3]+vb0);
            p1.x = cvtpk(D1[0]+vb1, D1[1]+vb1); p1.y = cvtpk(D1[2]+vb1, D1[3]+vb1);
            *(uint2*)&vt[h*2304 + c15*72        + tt*16 + g*4] = p0;
            *(uint2*)&vt[h*2304 + (16+c15)*72   + tt*16 + g*4] = p1;
        }
    }

    // ---- q,k swapped-operand MFMA: fragments straight into registers ----
    bh8 qf[4], kf[4];
    {
        bh8 aqf[2][4], akf[2][4];
        #pragma unroll
        for (int jt = 0; jt < 2; ++jt)
            #pragma unroll
            for (int kc = 0; kc < 4; ++kc) {
                aqf[jt][kc] = *(const bh8*)&ws[WS_QKV + (      h*32 + jt*16 + c15)*128 + kc*32 + g*8];
                akf[jt][kc] = *(const bh8*)&ws[WS_QKV + (128 + h*32 + jt*16 + c15)*128 + kc*32 + g*8];
            }
        const float4 qb0 = *(const float4*)(QB + h*32 + g*4);
        const float4 qb1 = *(const float4*)(QB + h*32 + 16 + g*4);
        const float4 kb0 = *(const float4*)(QB + 128 + h*32 + g*4);
        const float4 kb1 = *(const float4*)(QB + 128 + h*32 + 16 + g*4);
        #pragma unroll
        for (int tt = 0; tt < 4; ++tt) {
            bh8 xf[4];
            #pragma unroll
            for (int kc = 0; kc < 4; ++kc)
                xf[kc] = *(const bh8*)&arena[(tt*16 + c15)*136 + kc*32 + g*8];
            f32x4 Dq0={0,0,0,0}, Dq1={0,0,0,0}, Dk0={0,0,0,0}, Dk1={0,0,0,0};
            #pragma unroll
            for (int kc = 0; kc < 4; ++kc) {
                Dq0 = MFMA(aqf[0][kc], xf[kc], Dq0, 0,0,0);
                Dq1 = MFMA(aqf[1][kc], xf[kc], Dq1, 0,0,0);
                Dk0 = MFMA(akf[0][kc], xf[kc], Dk0, 0,0,0);
                Dk1 = MFMA(akf[1][kc], xf[kc], Dk1, 0,0,0);
            }
            BH8U qu, ku;
            qu.u[0] = cvtpk(Dq0[0]+qb0.x, Dq0[1]+qb0.y); qu.u[1] = cvtpk(Dq0[2]+qb0.z, Dq0[3]+qb0.w);
            qu.u[2] = cvtpk(Dq1[0]+qb1.x, Dq1[1]+qb1.y); qu.u[3] = cvtpk(Dq1[2]+qb1.z, Dq1[3]+qb1.w);
            ku.u[0] = cvtpk(Dk0[0]+kb0.x, Dk0[1]+kb0.y); ku.u[1] = cvtpk(Dk0[2]+kb0.z, Dk0[3]+kb0.w);
            ku.u[2] = cvtpk(Dk1[0]+kb1.x, Dk1[1]+kb1.y); ku.u[3] = cvtpk(Dk1[2]+kb1.z, Dk1[3]+kb1.w);
            qf[tt] = qu.v; kf[tt] = ku.v;
        }
    }
    __syncthreads();   // xn dead; P aliases arena

    // ---- QK^T with baked bias/mask as acc-init; softmax (no max pass) ----
    f32x4 p[4][4]; f32x4 inv4[4];
    #pragma unroll
    for (int rt = 0; rt < 4; ++rt) {
        #pragma unroll
        for (int ct = 0; ct < 4; ++ct) {
            f32x4 macc = *(const f32x4*)(Mb + (rt*4 + ct)*256 + lane*4);
            p[rt][ct] = MFMA(qf[rt], kf[ct], macc, 0,0,0);
        }
        #pragma unroll
        for (int ct = 0; ct < 4; ++ct)
            #pragma unroll
            for (int jr = 0; jr < 4; ++jr) p[rt][ct][jr] = __expf(p[rt][ct][jr]);
        f32x4 t = p[rt][0] + p[rt][1] + p[rt][2] + p[rt][3];
        #pragma unroll
        for (int jr = 0; jr < 4; ++jr) {
            float v = t[jr];
            v += __shfl_xor(v, 1); v += __shfl_xor(v, 2);
            v += __shfl_xor(v, 4); v += __shfl_xor(v, 8);
            inv4[rt][jr] = rcpf(v + 1e-30f);
        }
    }

    // ---- P (raw exp) -> swizzled LDS tile ----
    char* Pbase = (char*)arena + h * 8192;
    #pragma unroll
    for (int rt = 0; rt < 4; ++rt)
        #pragma unroll
        for (int jr = 0; jr < 4; ++jr) {
            const int row = rt*16 + g*4 + jr, sw = (row & 7) << 4;
            #pragma unroll
            for (int ct = 0; ct < 4; ++ct)
                *(u16*)(Pbase + ((row*128 + (ct*16 + c15)*2) ^ sw)) = f2bf(p[rt][ct][jr]);
        }
    asm volatile("s_waitcnt lgkmcnt(0)" ::: "memory");

    // ---- PV ----
    f32x4 o[4][2];
    #pragma unroll
    for (int rt = 0; rt < 4; ++rt) { o[rt][0] = (f32x4){0,0,0,0}; o[rt][1] = (f32x4){0,0,0,0}; }
    {
        bh8 vf[2][2];
        #pragma unroll
        for (int ct = 0; ct < 2; ++ct)
            #pragma unroll
            for (int kc = 0; kc < 2; ++kc)
                vf[ct][kc] = *(const bh8*)&vt[h*2304 + (ct*16 + c15)*72 + kc*32 + g*8];
        #pragma unroll
        for (int rt = 0; rt < 4; ++rt) {
            const int row = rt*16 + c15, sw = (row & 7) << 4;
            #pragma unroll
            for (int kc = 0; kc < 2; ++kc) {
                bh8 pa = *(const bh8*)(Pbase + ((row*128 + kc*64 + g*16) ^ sw));
                o[rt][0] = MFMA(pa, vf[0][kc], o[rt][0], 0,0,0);
                o[rt][1] = MFMA(pa, vf[1][kc], o[rt][1], 0,0,0);
            }
        }
    }
    __syncthreads();   // P reads + vt reads done; arena free for ao

    // ---- normalized attn-out -> ao ----
    #pragma unroll
    for (int rt = 0; rt < 4; ++rt)
        #pragma unroll
        for (int jr = 0; jr < 4; ++jr) {
            const int row = rt*16 + g*4 + jr;
            u32 pk_ = cvtpk(o[rt][0][jr] * inv4[rt][jr], o[rt][1][jr] * inv4[rt][jr]);
            *(u32*)&arena[row*136 + h*32 + 2*c15] = pk_;
        }
    __syncthreads();

    // ---- proj + residual + unshift scatter ----
    {
        bh8 wfp[2][4];
        #pragma unroll
        for (int ct2 = 0; ct2 < 2; ++ct2)
            #pragma unroll
            for (int kc = 0; kc < 4; ++kc)
                wfp[ct2][kc] = *(const bh8*)&ws[WS_PROJ + (h*32 + ct2*16 + c15)*128 + kc*32 + g*8];
        f32x4 pacc[4][2];
        #pragma unroll
        for (int rt = 0; rt < 4; ++rt) { pacc[rt][0] = (f32x4){0,0,0,0}; pacc[rt][1] = (f32x4){0,0,0,0}; }
        #pragma unroll
        for (int rt = 0; rt < 4; ++rt) {
            bh8 af[4];
            #pragma unroll
            for (int kc = 0; kc < 4; ++kc)
                af[kc] = *(const bh8*)&arena[(rt*16 + c15)*136 + kc*32 + g*8];
            #pragma unroll
            for (int kc = 0; kc < 4; ++kc) {
                pacc[rt][0] = MFMA(af[kc], wfp[0][kc], pacc[rt][0], 0,0,0);
                pacc[rt][1] = MFMA(af[kc], wfp[1][kc], pacc[rt][1], 0,0,0);
            }
        }
        const int col0 = h*32 + c15, col1 = col0 + 16;
        const float pb0 = projb[col0], pb1 = projb[col1];
        #pragma unroll
        for (int rt = 0; rt < 4; ++rt)
            #pragma unroll
            for (int jr = 0; jr < 4; ++jr) {
                const int t = rt*16 + g*4 + jr;
                if (t < 49) {
                    const int td = (t * 37) >> 8, tm = t - td * 7;
                    int hs = hb*7 + td + 3;  if (hs >= 112) hs -= 112;
                    int wsw = wb*7 + tm + 3; if (wsw >= 112) wsw -= 112;
                    const size_t base = (size_t)((b*112 + hs)*112 + wsw) * 128;
                    out[base + col0] = pacc[rt][0][jr] + pb0 + x[base + col0];
                    out[base + col1] = pacc[rt][1][jr] + pb1 + x[base + col1];
                }
            }
    }
}

// ---------------------------------------------------------------------------
// MLP: 64 tokens/block, 4 waves. Software-pipelined chunks with double-
// buffered hbuf: phase c runs fc1(c) AND fc2(c-1) (independent -> MFMA/VALU
// overlap). LN2 folded, A&S GELU. 52.7 KB LDS -> 3 blocks/CU. In-place.
// ---------------------------------------------------------------------------
__global__ __launch_bounds__(256, 3) void swin_mlp_k(
    float* __restrict__ xio, const float* __restrict__ f2b, const u16* __restrict__ ws)
{
    __shared__ u16 xnb[64 * 136];     // raw x1, bf16
    __shared__ u16 hb0[64 * 136];     // gelu(fc1) ping
    __shared__ u16 hb1[64 * 136];     // gelu(fc1) pong
    __shared__ float2 stats[64];      // {rstd, rstd*mean}
    const int tid = threadIdx.x, w = tid >> 6, lane = tid & 63;
    const int c15 = lane & 15, g = lane >> 4;
    const size_t tok0 = (size_t)blockIdx.x * 64;
    const float* S1 = (const float*)(ws + WS_S1);
    const float* T1 = (const float*)(ws + WS_T1);

    // fc1 weights for chunk 0 (issued first; latency overlaps the LN pass)
    bh8 wf1[2][4];
    #pragma unroll
    for (int jt = 0; jt < 2; ++jt)
        #pragma unroll
        for (int kc = 0; kc < 4; ++kc)
            wf1[jt][kc] = *(const bh8*)&ws[WS_F1 + (w*32 + jt*16 + c15)*128 + kc*32 + g*8];

    // ---- stats + raw x1 -> bf16 LDS (4-lane teams) ----
    {
        const int t = tid >> 2, ss = tid & 3;
        const float* px = xio + (tok0 + t) * 128 + ss * 32;
        float4 xv[8];
        #pragma unroll
        for (int i = 0; i < 8; ++i) xv[i] = *(const float4*)(px + i * 4);
        float s = 0.f, q = 0.f;
        #pragma unroll
        for (int i = 0; i < 8; ++i) {
            s += xv[i].x + xv[i].y + xv[i].z + xv[i].w;
            q += xv[i].x*xv[i].x + xv[i].y*xv[i].y + xv[i].z*xv[i].z + xv[i].w*xv[i].w;
        }
        s += __shfl_xor(s, 1); q += __shfl_xor(q, 1);
        s += __shfl_xor(s, 2); q += __shfl_xor(q, 2);
        float mean = s * (1.f/128.f), var = q * (1.f/128.f) - mean * mean;
        float rstd = rsqrtf(var + 1e-5f);
        #pragma unroll
        for (int i = 0; i < 4; ++i) {
            float4 a = xv[2*i], c = xv[2*i+1];
            uint4 wv;
            wv.x = cvtpk(a.x, a.y); wv.y = cvtpk(a.z, a.w);
            wv.z = cvtpk(c.x, c.y); wv.w = cvtpk(c.z, c.w);
            *(uint4*)&xnb[t * 136 + ss * 32 + i * 8] = wv;
        }
        if (ss == 0) stats[t] = (float2){rstd, rstd * mean};
    }
    __syncthreads();

    f32x4 acc[4][2];
    #pragma unroll
    for (int rt = 0; rt < 4; ++rt) { acc[rt][0] = (f32x4){0,0,0,0}; acc[rt][1] = (f32x4){0,0,0,0}; }
    bh8 wf2[2][4];

    auto LD_W1 = [&](int chunk) {
        #pragma unroll
        for (int jt = 0; jt < 2; ++jt)
            #pragma unroll
            for (int kc = 0; kc < 4; ++kc)
                wf1[jt][kc] = *(const bh8*)&ws[WS_F1 + (chunk*128 + w*32 + jt*16 + c15)*128 + kc*32 + g*8];
    };
    auto LD_W2 = [&](int chunk) {
        #pragma unroll
        for (int ct2 = 0; ct2 < 2; ++ct2)
            #pragma unroll
            for (int kc = 0; kc < 4; ++kc)
                wf2[ct2][kc] = *(const bh8*)&ws[WS_F2 + (w*32 + ct2*16 + c15)*512 + chunk*128 + kc*32 + g*8];
    };
    auto FC1 = [&](int chunk, u16* hb) {
        const float s1a = S1[chunk*128 + w*32 + c15], s1b = S1[chunk*128 + w*32 + 16 + c15];
        const float t1a = T1[chunk*128 + w*32 + c15], t1b = T1[chunk*128 + w*32 + 16 + c15];
        #pragma unroll
        for (int rt = 0; rt < 4; ++rt) {
            bh8 af[4];
            #pragma unroll
            for (int kc = 0; kc < 4; ++kc)
                af[kc] = *(const bh8*)&xnb[(rt*16 + c15)*136 + kc*32 + g*8];
            f32x4 D0 = {0,0,0,0}, D1 = {0,0,0,0};
            #pragma unroll
            for (int kc = 0; kc < 4; ++kc) { D0 = MFMA(af[kc], wf1[0][kc], D0, 0,0,0); D1 = MFMA(af[kc], wf1[1][kc], D1, 0,0,0); }
            #pragma unroll
            for (int jr = 0; jr < 4; ++jr) {
                const int row = rt*16 + g*4 + jr;
                float2 st = stats[row];
                float h0 = gelu_f(fmaf(st.x, D0[jr], fmaf(-st.y, s1a, t1a)));
                float h1 = gelu_f(fmaf(st.x, D1[jr], fmaf(-st.y, s1b, t1b)));
                *(u32*)&hb[row*136 + w*32 + 2*c15] = cvtpk(h0, h1);
            }
        }
    };
    auto FC2 = [&](const u16* hb) {
        #pragma unroll
        for (int rt = 0; rt < 4; ++rt) {
            bh8 ha[4];
            #pragma unroll
            for (int kc = 0; kc < 4; ++kc)
                ha[kc] = *(const bh8*)&hb[(rt*16 + c15)*136 + kc*32 + g*8];
            #pragma unroll
            for (int kc = 0; kc < 4; ++kc) {
                acc[rt][0] = MFMA(ha[kc], wf2[0][kc], acc[rt][0], 0,0,0);
                acc[rt][1] = MFMA(ha[kc], wf2[1][kc], acc[rt][1], 0,0,0);
            }
        }
    };

    // phase 1: fc1(0)
    FC1(0, hb0);
    LD_W1(1);
    __syncthreads();
    // phase 2: fc1(1) || fc2(0)
    LD_W2(0);
    FC1(1, hb1);
    LD_W1(2);
    FC2(hb0);
    __syncthreads();
    // phase 3: fc1(2) || fc2(1)
    LD_W2(1);
    FC1(2, hb0);
    LD_W1(3);
    FC2(hb1);
    __syncthreads();
    // phase 4: fc1(3) || fc2(2)
    LD_W2(2);
    FC1(3, hb1);
    FC2(hb0);
    __syncthreads();
    // phase 5: fc2(3)
    LD_W2(3);
    FC2(hb1);

    // ---- residual (in place) ----
    const int col0 = w*32 + c15, col1 = col0 + 16;
    const float cb0 = f2b[col0], cb1 = f2b[col1];
    #pragma unroll
    for (int rt = 0; rt < 4; ++rt)
        #pragma unroll
        for (int jr = 0; jr < 4; ++jr) {
            const size_t r = (tok0 + rt*16 + g*4 + jr) * 128;
            xio[r + col0] += acc[rt][0][jr] + cb0;
            xio[r + col1] += acc[rt][1][jr] + cb1;
        }
}

extern "C" void kernel_launch(void* const* d_in, const int* in_sizes, int n_in,
                              void* d_out, int out_size, void* d_ws, size_t ws_size,
                              hipStream_t stream)
{
    const float* x    = (const float*)d_in[0];
    const float* n1g  = (const float*)d_in[1];
    const float* n1b  = (const float*)d_in[2];
    const float* qkvw = (const float*)d_in[3];
    const float* qkvb = (const float*)d_in[4];
    const float* rel  = (const float*)d_in[5];
    const float* pw   = (const float*)d_in[6];
    const float* pb   = (const float*)d_in[7];
    const float* n2g  = (const float*)d_in[8];
    const float* n2b  = (const float*)d_in[9];
    const float* f1w  = (const float*)d_in[10];
    const float* f1b  = (const float*)d_in[11];
    const float* f2w  = (const float*)d_in[12];
    const float* f2b  = (const float*)d_in[13];
    float* out = (float*)d_out;
    u16* ws = (u16*)d_ws;

    prep_k<<<1028, 256, 0, stream>>>(qkvw, pw, f1w, f2w, rel, qkvb, n2g, n2b, f1b, ws);
    swin_attn_k<<<4096, 256, 0, stream>>>(x, n1g, n1b, pb, ws, out);
    swin_mlp_k<<<3136, 256, 0, stream>>>(out, f2b, ws);
}